// Round 1
// 329.344 us; speedup vs baseline: 1.0843x; 1.0843x over previous
//
#include <hip/hip_runtime.h>
#include <hip/hip_bf16.h>

// ---- problem constants ----
#define DB   2
#define DS   2048
#define DH   2048
#define DNH  32
#define DKVH 8
#define DHD  64
#define DM   4096    // B*S
#define DNQKV 3072   // NH*HD + 2*KVH*HD

typedef __attribute__((ext_vector_type(8))) short bf16x8;
typedef __attribute__((ext_vector_type(4))) float f32x4;
typedef __attribute__((ext_vector_type(8))) unsigned short us8;
typedef __attribute__((ext_vector_type(4))) unsigned short us4;

__device__ __forceinline__ float b2f(unsigned short u) {
  unsigned int x = ((unsigned int)u) << 16;
  return __builtin_bit_cast(float, x);
}
__device__ __forceinline__ unsigned short f2b(float f) {
  unsigned int u = __builtin_bit_cast(unsigned int, f);
  return (unsigned short)((u + 0x8000u) >> 16);
}
__device__ __forceinline__ void async_copy16(void* lds, const void* g) {
  __builtin_amdgcn_global_load_lds((const __attribute__((address_space(1))) void*)g,
                                   (__attribute__((address_space(3))) void*)lds,
                                   16, 0, 0);
}

// raw barrier (no waitcnt drain) + compiler memory fences
#define BARRIER() do { asm volatile("" ::: "memory"); __builtin_amdgcn_s_barrier(); asm volatile("" ::: "memory"); } while (0)
#define LGKM0()   asm volatile("s_waitcnt lgkmcnt(0)" ::: "memory")
#define WAITVM(n) asm volatile("s_waitcnt vmcnt(" #n ")" ::: "memory")
#define MFMA16(d, a, bb) (d) = __builtin_amdgcn_mfma_f32_16x16x32_bf16((a), (bb), (d), 0, 0, 0)

// ---- dtype detector ----
__global__ void detect_mode(const unsigned short* __restrict__ w, int* __restrict__ flags) {
  int t = threadIdx.x;
  int trips = 0;
  for (int i = 0; i < 4; i++) {
    unsigned short u = w[t * 4 + i];
    int e = (u >> 7) & 0xFF;
    if (e >= 161 || (e <= 93 && e != 0)) trips++;
  }
  for (int off = 32; off > 0; off >>= 1) trips += __shfl_down(trips, off);
  if (t == 0) flags[0] = (trips >= 8) ? 1 : 0;  // 1 = fp32 I/O, 0 = bf16
}

// ---- X -> bf16 ----
__global__ __launch_bounds__(256) void convert_x(const void* __restrict__ xin,
                                                 unsigned short* __restrict__ xb,
                                                 const int* __restrict__ flags, int n) {
  int mode = flags[0];
  int i = (blockIdx.x * 256 + threadIdx.x) * 8;
  if (i >= n) return;
  if (mode) {
    const float* f = (const float*)xin;
    us8 o;
#pragma unroll
    for (int j = 0; j < 8; j++) o[j] = f2b(f[i + j]);
    *(us8*)&xb[i] = o;
  } else {
    *(us8*)&xb[i] = *(const us8*)((const unsigned short*)xin + i);
  }
}

// ---- W [R][C] -> bf16 W^T [C][R] ----
__global__ __launch_bounds__(256) void transpose_w(const void* __restrict__ win,
                                                   unsigned short* __restrict__ out,
                                                   const int* __restrict__ flags,
                                                   int R, int C) {
  __shared__ float tile[32][33];
  int mode = flags[0];
  int c0 = blockIdx.x * 32, r0 = blockIdx.y * 32;
  int tx = threadIdx.x & 31, ty = threadIdx.x >> 5;
  if (mode) {
    const float* f = (const float*)win;
    for (int i = ty; i < 32; i += 8) tile[i][tx] = f[(size_t)(r0 + i) * C + c0 + tx];
  } else {
    const unsigned short* bsrc = (const unsigned short*)win;
    for (int i = ty; i < 32; i += 8) tile[i][tx] = b2f(bsrc[(size_t)(r0 + i) * C + c0 + tx]);
  }
  __syncthreads();
  for (int i = ty; i < 32; i += 8) out[(size_t)(c0 + i) * R + r0 + tx] = f2b(tile[tx][i]);
}

#define QSC 0.18033688011112042f   // (1/8) * log2(e)

// ============================================================================
// 8-phase 256x256 QKV GEMM + RoPE + head-major scatter.
// BK=64 split into 2 kh-units of 32 cols. LDS 128KB: [buf][kh] A-units (256x32)
// then B-units. XOR swizzle cc^=(row>>1)&3 applied on global source (staging)
// and on ds_read address => 2-way max bank aliasing (free).
// Counted vmcnt(8) only twice per K-tile; raw barriers; setprio around MFMA.
// ============================================================================
__global__ __launch_bounds__(512, 2)
void gemm_qkv(const unsigned short* __restrict__ A, const unsigned short* __restrict__ Bt,
              const int* __restrict__ pos_ids,
              unsigned short* __restrict__ qws, unsigned short* __restrict__ kws,
              unsigned short* __restrict__ vt) {
  __shared__ __align__(16) unsigned short sm[65536];  // 128 KiB
  int tid = threadIdx.x, lane = tid & 63, wave = tid >> 6;
  int wm = wave >> 2, wn = wave & 3;           // 2 x 4 waves, wave tile 128x64
  int quad = lane >> 4, l15 = lane & 15;

  int bid = blockIdx.x;                         // 192 blocks, 192 % 8 == 0
  int wg = (bid & 7) * 24 + (bid >> 3);         // XCD-contiguous chunks of 24
  int ty = wg / 12, tx = wg - ty * 12;
  size_t tm0 = (size_t)ty * 256, tn0 = (size_t)tx * 256;

  const unsigned short* Ab = A + tm0 * 2048;
  const unsigned short* Bb = Bt + tn0 * 2048;

  auto UA = [&](int bu, int kh) { return sm + (bu * 2 + kh) * 8192; };
  auto UB = [&](int bu, int kh) { return sm + 32768 + (bu * 2 + kh) * 8192; };

  // staging: chunk c (16B) -> LDS linear, global col-chunk = (c&3) ^ ((row>>1)&3)
  int c0 = tid, c1 = tid + 512;
  int r0s = c0 >> 2, r1s = c1 >> 2;
  int cc0 = (c0 & 3) ^ ((r0s >> 1) & 3);
  int cc1 = (c1 & 3) ^ ((r1s >> 1) & 3);
  size_t ga0 = (size_t)r0s * 2048 + cc0 * 8;
  size_t ga1 = (size_t)r1s * 2048 + cc1 * 8;

  auto stA = [&](int t, int kh, int bu) {
    const unsigned short* s = Ab + (size_t)t * 64 + kh * 32;
    async_copy16(UA(bu, kh) + c0 * 8, s + ga0);
    async_copy16(UA(bu, kh) + c1 * 8, s + ga1);
  };
  auto stB = [&](int t, int kh, int bu) {
    const unsigned short* s = Bb + (size_t)t * 64 + kh * 32;
    async_copy16(UB(bu, kh) + c0 * 8, s + ga0);
    async_copy16(UB(bu, kh) + c1 * 8, s + ga1);
  };

  // ds_read lane offset (shorts) inside a unit, with matching XOR swizzle
  int rdoff = l15 * 32 + ((quad << 3) ^ (((l15 >> 1) & 3) << 3));

  f32x4 zero4 = {0.f, 0.f, 0.f, 0.f};
  f32x4 acc[8][4];
#pragma unroll
  for (int mi = 0; mi < 8; mi++)
#pragma unroll
    for (int ni = 0; ni < 4; ni++) acc[mi][ni] = zero4;

  // prologue: issue t0.{A0,B0,A1,B1}, t1.{A0,B0}; wait first 2 units (8 newer outstanding)
  stA(0, 0, 0); stB(0, 0, 0); stA(0, 1, 0); stB(0, 1, 0); stA(1, 0, 1); stB(1, 0, 1);
  WAITVM(8); BARRIER();

#pragma unroll 2
  for (int t = 0; t < 32; ++t) {
    int bu = t & 1, bn = bu ^ 1;
    int t1 = (t + 1 < 32) ? t + 1 : 31;   // clamped dummy stages keep vmcnt uniform
    int t2 = (t + 2 < 32) ? t + 2 : 31;
    bf16x8 af[8];
    const unsigned short* pA0 = UA(bu, 0) + wm * 4096 + rdoff;
    const unsigned short* pB0 = UB(bu, 0) + wn * 2048 + rdoff;
    const unsigned short* pA1 = UA(bu, 1) + wm * 4096 + rdoff;
    const unsigned short* pB1 = UB(bu, 1) + wn * 2048 + rdoff;

    // ---- phase 0: kh0, n-frags {0,1}; stage (t+1).A.kh1 ----
#pragma unroll
    for (int mi = 0; mi < 8; mi++) af[mi] = *(const bf16x8*)(pA0 + mi * 512);
    bf16x8 b0 = *(const bf16x8*)pB0;
    bf16x8 b1 = *(const bf16x8*)(pB0 + 512);
    stA(t1, 1, bn);
    BARRIER(); LGKM0();
    __builtin_amdgcn_s_setprio(1);
#pragma unroll
    for (int mi = 0; mi < 8; mi++) { MFMA16(acc[mi][0], af[mi], b0); MFMA16(acc[mi][1], af[mi], b1); }
    __builtin_amdgcn_s_setprio(0);
    BARRIER();

    // ---- phase 1: kh0, n-frags {2,3}; stage (t+1).B.kh1; checkpoint C1 ----
    bf16x8 b2 = *(const bf16x8*)(pB0 + 1024);
    bf16x8 b3 = *(const bf16x8*)(pB0 + 1536);
    stB(t1, 1, bn);
    BARRIER(); LGKM0();
    __builtin_amdgcn_s_setprio(1);
#pragma unroll
    for (int mi = 0; mi < 8; mi++) { MFMA16(acc[mi][2], af[mi], b2); MFMA16(acc[mi][3], af[mi], b3); }
    __builtin_amdgcn_s_setprio(0);
    WAITVM(8);   // tile t kh1 units landed; 4 newer units stay in flight
    BARRIER();

    // ---- phase 2: kh1, n-frags {0,1}; stage (t+2).A.kh0 ----
#pragma unroll
    for (int mi = 0; mi < 8; mi++) af[mi] = *(const bf16x8*)(pA1 + mi * 512);
    b0 = *(const bf16x8*)pB1;
    b1 = *(const bf16x8*)(pB1 + 512);
    stA(t2, 0, bu);
    BARRIER(); LGKM0();
    __builtin_amdgcn_s_setprio(1);
#pragma unroll
    for (int mi = 0; mi < 8; mi++) { MFMA16(acc[mi][0], af[mi], b0); MFMA16(acc[mi][1], af[mi], b1); }
    __builtin_amdgcn_s_setprio(0);
    BARRIER();

    // ---- phase 3: kh1, n-frags {2,3}; stage (t+2).B.kh0; checkpoint C2 ----
    b2 = *(const bf16x8*)(pB1 + 1024);
    b3 = *(const bf16x8*)(pB1 + 1536);
    stB(t2, 0, bu);
    BARRIER(); LGKM0();
    __builtin_amdgcn_s_setprio(1);
#pragma unroll
    for (int mi = 0; mi < 8; mi++) { MFMA16(acc[mi][2], af[mi], b2); MFMA16(acc[mi][3], af[mi], b3); }
    __builtin_amdgcn_s_setprio(0);
    WAITVM(8);   // tile t+1 kh0 units landed
    BARRIER();
  }
  WAITVM(0);

  // ---- epilogue: RoPE for Q/K slots, transposed scatter for V ----
  int hs = (int)(tn0 >> 6) + wn;  // head slot 0..47 (wave-uniform)
  if (hs < 40) {
    float sc = (hs < 32) ? QSC : 1.0f;
    unsigned short* dst0 = (hs < 32) ? qws : kws;
    int hh = (hs < 32) ? hs : (hs - 32);
    float invf0 = __expf(-(float)l15 * (9.210340371976184f / 32.0f));
    float invf1 = invf0 * 0.01f;
#pragma unroll
    for (int mi = 0; mi < 8; mi++)
#pragma unroll
      for (int r = 0; r < 4; r++) {
        size_t gr = tm0 + wm * 128 + mi * 16 + quad * 4 + r;
        int bb = (int)(gr >> 11), s = (int)(gr & 2047);
        float tpos = (float)pos_ids[gr];
        unsigned short* row = dst0 + ((size_t)(bb * ((hs < 32) ? DNH : DKVH) + hh) * DS + s) * DHD;
#pragma unroll
        for (int ni = 0; ni < 2; ni++) {
          float x1 = acc[mi][ni][r], x2 = acc[mi][ni + 2][r];
          float ang = tpos * (ni ? invf1 : invf0);
          float sn, cs;
          __sincosf(ang, &sn, &cs);
          int d = ni * 16 + l15;
          row[d]      = f2b((x1 * cs - x2 * sn) * sc);
          row[d + 32] = f2b((x2 * cs + x1 * sn) * sc);
        }
      }
  } else {
    int vh = hs - 40;
    int bb = (int)(tm0 >> 11);
    int s0 = (int)(tm0 & 2047) + wm * 128 + quad * 4;
#pragma unroll
    for (int mi = 0; mi < 8; mi++)
#pragma unroll
      for (int ni = 0; ni < 4; ni++) {
        int d = ni * 16 + l15;
        us4 o4;
#pragma unroll
        for (int r = 0; r < 4; r++) o4[r] = f2b(acc[mi][ni][r]);
        *(us4*)&vt[((size_t)(bb * DKVH + vh) * DHD + d) * DS + s0 + mi * 16] = o4;
      }
  }
}

// ============================================================================
// 8-phase 128x256 out GEMM: d_out[M,N] = ctx * Wo^T. Same schedule; A-unit is
// 128x32 (1 load/thread), B-unit 256x32 (2 loads) => vmcnt(6). LDS 96KB.
// ============================================================================
__global__ __launch_bounds__(512, 2)
void gemm_out(const unsigned short* __restrict__ A, const unsigned short* __restrict__ Bt,
              unsigned short* __restrict__ Cb, float* __restrict__ Cf,
              const int* __restrict__ outmode) {
  __shared__ __align__(16) unsigned short sm[49152];  // 96 KiB
  int tid = threadIdx.x, lane = tid & 63, wave = tid >> 6;
  int wm = wave >> 2, wn = wave & 3;           // wave tile 64x64
  int quad = lane >> 4, l15 = lane & 15;

  int bid = blockIdx.x;                         // 256 blocks
  int wg = (bid & 7) * 32 + (bid >> 3);
  int ty = wg >> 3, tx = wg & 7;
  size_t tm0 = (size_t)ty * 128, tn0 = (size_t)tx * 256;

  const unsigned short* Ab = A + tm0 * 2048;
  const unsigned short* Bb = Bt + tn0 * 2048;

  auto UA = [&](int bu, int kh) { return sm + (bu * 2 + kh) * 4096; };
  auto UB = [&](int bu, int kh) { return sm + 16384 + (bu * 2 + kh) * 8192; };

  int c0 = tid, c1 = tid + 512;
  int r0s = c0 >> 2, r1s = c1 >> 2;
  int cc0 = (c0 & 3) ^ ((r0s >> 1) & 3);
  int cc1 = (c1 & 3) ^ ((r1s >> 1) & 3);
  size_t ga0 = (size_t)r0s * 2048 + cc0 * 8;
  size_t ga1 = (size_t)r1s * 2048 + cc1 * 8;

  auto stA = [&](int t, int kh, int bu) {      // 128 rows: 1 load/thread
    const unsigned short* s = Ab + (size_t)t * 64 + kh * 32;
    async_copy16(UA(bu, kh) + c0 * 8, s + ga0);
  };
  auto stB = [&](int t, int kh, int bu) {      // 256 rows: 2 loads/thread
    const unsigned short* s = Bb + (size_t)t * 64 + kh * 32;
    async_copy16(UB(bu, kh) + c0 * 8, s + ga0);
    async_copy16(UB(bu, kh) + c1 * 8, s + ga1);
  };

  int rdoff = l15 * 32 + ((quad << 3) ^ (((l15 >> 1) & 3) << 3));

  f32x4 zero4 = {0.f, 0.f, 0.f, 0.f};
  f32x4 acc[4][4];
#pragma unroll
  for (int mi = 0; mi < 4; mi++)
#pragma unroll
    for (int ni = 0; ni < 4; ni++) acc[mi][ni] = zero4;

  stA(0, 0, 0); stB(0, 0, 0); stA(0, 1, 0); stB(0, 1, 0); stA(1, 0, 1); stB(1, 0, 1);
  WAITVM(6); BARRIER();

#pragma unroll 2
  for (int t = 0; t < 32; ++t) {
    int bu = t & 1, bn = bu ^ 1;
    int t1 = (t + 1 < 32) ? t + 1 : 31;
    int t2 = (t + 2 < 32) ? t + 2 : 31;
    bf16x8 af[4];
    const unsigned short* pA0 = UA(bu, 0) + wm * 2048 + rdoff;
    const unsigned short* pB0 = UB(bu, 0) + wn * 2048 + rdoff;
    const unsigned short* pA1 = UA(bu, 1) + wm * 2048 + rdoff;
    const unsigned short* pB1 = UB(bu, 1) + wn * 2048 + rdoff;

    // p0
#pragma unroll
    for (int mi = 0; mi < 4; mi++) af[mi] = *(const bf16x8*)(pA0 + mi * 512);
    bf16x8 b0 = *(const bf16x8*)pB0;
    bf16x8 b1 = *(const bf16x8*)(pB0 + 512);
    stA(t1, 1, bn);
    BARRIER(); LGKM0();
    __builtin_amdgcn_s_setprio(1);
#pragma unroll
    for (int mi = 0; mi < 4; mi++) { MFMA16(acc[mi][0], af[mi], b0); MFMA16(acc[mi][1], af[mi], b1); }
    __builtin_amdgcn_s_setprio(0);
    BARRIER();

    // p1 (checkpoint C1)
    bf16x8 b2 = *(const bf16x8*)(pB0 + 1024);
    bf16x8 b3 = *(const bf16x8*)(pB0 + 1536);
    stB(t1, 1, bn);
    BARRIER(); LGKM0();
    __builtin_amdgcn_s_setprio(1);
#pragma unroll
    for (int mi = 0; mi < 4; mi++) { MFMA16(acc[mi][2], af[mi], b2); MFMA16(acc[mi][3], af[mi], b3); }
    __builtin_amdgcn_s_setprio(0);
    WAITVM(6);
    BARRIER();

    // p2
#pragma unroll
    for (int mi = 0; mi < 4; mi++) af[mi] = *(const bf16x8*)(pA1 + mi * 512);
    b0 = *(const bf16x8*)pB1;
    b1 = *(const bf16x8*)(pB1 + 512);
    stA(t2, 0, bu);
    BARRIER(); LGKM0();
    __builtin_amdgcn_s_setprio(1);
#pragma unroll
    for (int mi = 0; mi < 4; mi++) { MFMA16(acc[mi][0], af[mi], b0); MFMA16(acc[mi][1], af[mi], b1); }
    __builtin_amdgcn_s_setprio(0);
    BARRIER();

    // p3 (checkpoint C2)
    b2 = *(const bf16x8*)(pB1 + 1024);
    b3 = *(const bf16x8*)(pB1 + 1536);
    stB(t2, 0, bu);
    BARRIER(); LGKM0();
    __builtin_amdgcn_s_setprio(1);
#pragma unroll
    for (int mi = 0; mi < 4; mi++) { MFMA16(acc[mi][2], af[mi], b2); MFMA16(acc[mi][3], af[mi], b3); }
    __builtin_amdgcn_s_setprio(0);
    WAITVM(6);
    BARRIER();
  }
  WAITVM(0);

  int mode = *outmode;
#pragma unroll
  for (int mi = 0; mi < 4; mi++)
#pragma unroll
    for (int ni = 0; ni < 4; ni++)
#pragma unroll
      for (int r = 0; r < 4; r++) {
        size_t gr = tm0 + wm * 64 + mi * 16 + quad * 4 + r;
        size_t gc = tn0 + wn * 64 + ni * 16 + l15;
        float v = acc[mi][ni][r];
        if (mode) Cf[gr * 2048 + gc] = v;
        else      Cb[gr * 2048 + gc] = f2b(v);
      }
}

// ---- causal GQA flash attention (S^T form, paired q-tiles) ----
__global__ __launch_bounds__(256, 4)
void flash_attn(const unsigned short* __restrict__ q, const unsigned short* __restrict__ k,
                const unsigned short* __restrict__ vt, unsigned short* __restrict__ ctx) {
  __shared__ __align__(16) unsigned short lK0[64 * 32];
  __shared__ __align__(16) unsigned short lK1[64 * 32];
  __shared__ __align__(16) unsigned short lV0[64 * 32];
  __shared__ __align__(16) unsigned short lV1[64 * 32];
  __shared__ __align__(16) unsigned short lP[4 * 16 * 72];
  int tid = threadIdx.x, lane = tid & 63, wave = tid >> 6;
  int quad = lane >> 4, l15 = lane & 15;
  int bh = blockIdx.y, b = bh >> 5, h = bh & 31, kvh = h >> 2;
  const unsigned short* qb = q + (size_t)(b * DNH + h) * DS * DHD;
  const unsigned short* kb = k + (size_t)(b * DKVH + kvh) * DS * DHD;
  const unsigned short* vb = vt + (size_t)(b * DKVH + kvh) * DHD * DS;
  unsigned short* lPw = lP + wave * 16 * 72;
  int r4 = tid >> 2, c8 = (tid & 3) * 8;

  f32x4 zero4 = {0.f, 0.f, 0.f, 0.f};
  for (int ph = 0; ph < 2; ph++) {
    int qt = ph ? (31 - blockIdx.x) : blockIdx.x;
    int q0 = qt * 64;
    const unsigned short* qp = qb + (size_t)(q0 + wave * 16 + l15) * DHD + quad * 8;
    bf16x8 qf0 = *(const bf16x8*)qp;
    bf16x8 qf1 = *(const bf16x8*)(qp + 32);
    f32x4 oacc[4];
#pragma unroll
    for (int dj = 0; dj < 4; dj++) oacc[dj] = zero4;
    float mrow = -1e30f, lrow = 0.f;

    int nt = qt + 1;
    for (int t = 0; t < nt; t++) {
      int kv0 = t * 64;
      __syncthreads();
      async_copy16(&lK0[tid * 8], kb + (size_t)(kv0 + r4) * DHD + c8);
      async_copy16(&lK1[tid * 8], kb + (size_t)(kv0 + r4) * DHD + 32 + c8);
      async_copy16(&lV0[tid * 8], vb + (size_t)r4 * DS + kv0 + c8);
      async_copy16(&lV1[tid * 8], vb + (size_t)r4 * DS + kv0 + 32 + c8);
      __syncthreads();

      f32x4 sacc[4];
#pragma unroll
      for (int nj = 0; nj < 4; nj++) {
        sacc[nj] = zero4;
        bf16x8 kf0 = *(const bf16x8*)&lK0[(nj * 16 + l15) * 32 + quad * 8];
        bf16x8 kf1 = *(const bf16x8*)&lK1[(nj * 16 + l15) * 32 + quad * 8];
        sacc[nj] = __builtin_amdgcn_mfma_f32_16x16x32_bf16(kf0, qf0, sacc[nj], 0, 0, 0);
        sacc[nj] = __builtin_amdgcn_mfma_f32_16x16x32_bf16(kf1, qf1, sacc[nj], 0, 0, 0);
      }
      if (t == nt - 1) {
        int ql = wave * 16 + l15;
#pragma unroll
        for (int nj = 0; nj < 4; nj++)
#pragma unroll
          for (int r = 0; r < 4; r++)
            if (nj * 16 + quad * 4 + r > ql) sacc[nj][r] = -1e30f;
      }
      float tm = -1e30f;
#pragma unroll
      for (int nj = 0; nj < 4; nj++)
#pragma unroll
        for (int r = 0; r < 4; r++) tm = fmaxf(tm, sacc[nj][r]);
      tm = fmaxf(tm, __shfl_xor(tm, 16));
      tm = fmaxf(tm, __shfl_xor(tm, 32));
      float mn = fmaxf(mrow, tm);
      float alpha = __builtin_amdgcn_exp2f(mrow - mn);
      mrow = mn;
      float rs = 0.f;
      float p[4][4];
#pragma unroll
      for (int nj = 0; nj < 4; nj++)
#pragma unroll
        for (int r = 0; r < 4; r++) {
          float e = __builtin_amdgcn_exp2f(sacc[nj][r] - mn);
          p[nj][r] = e;
          rs += e;
        }
      rs += __shfl_xor(rs, 16);
      rs += __shfl_xor(rs, 32);
      lrow = lrow * alpha + rs;
#pragma unroll
      for (int nj = 0; nj < 4; nj++) {
        us4 w4;
#pragma unroll
        for (int r = 0; r < 4; r++) w4[r] = f2b(p[nj][r]);
        *(us4*)&lPw[l15 * 72 + nj * 16 + quad * 4] = w4;
      }
      bf16x8 pf0 = *(const bf16x8*)&lPw[l15 * 72 + quad * 8];
      bf16x8 pf1 = *(const bf16x8*)&lPw[l15 * 72 + 32 + quad * 8];
#pragma unroll
      for (int dj = 0; dj < 4; dj++) {
#pragma unroll
        for (int r = 0; r < 4; r++) oacc[dj][r] *= alpha;
        bf16x8 vf0 = *(const bf16x8*)&lV0[(dj * 16 + l15) * 32 + quad * 8];
        bf16x8 vf1 = *(const bf16x8*)&lV1[(dj * 16 + l15) * 32 + quad * 8];
        oacc[dj] = __builtin_amdgcn_mfma_f32_16x16x32_bf16(vf0, pf0, oacc[dj], 0, 0, 0);
        oacc[dj] = __builtin_amdgcn_mfma_f32_16x16x32_bf16(vf1, pf1, oacc[dj], 0, 0, 0);
      }
    }
    float inv = __builtin_amdgcn_rcpf(lrow);
    size_t orow = ((size_t)b * DS + q0 + wave * 16 + l15) * (DNH * DHD) + (size_t)h * DHD;
#pragma unroll
    for (int dj = 0; dj < 4; dj++) {
      us4 o4;
#pragma unroll
      for (int r = 0; r < 4; r++) o4[r] = f2b(oacc[dj][r] * inv);
      *(us4*)&ctx[orow + dj * 16 + quad * 4] = o4;
    }
  }
}

extern "C" void kernel_launch(void* const* d_in, const int* in_sizes, int n_in,
                              void* d_out, int out_size, void* d_ws, size_t ws_size,
                              hipStream_t stream) {
  (void)in_sizes; (void)n_in; (void)out_size; (void)ws_size;
  const void* hs = d_in[0];
  const int* pos = (const int*)d_in[2];
  const void* wq = d_in[3];
  const void* wk = d_in[4];
  const void* wv = d_in[5];
  const void* wo = d_in[6];

  char* ws = (char*)d_ws;
  size_t off = 0;
  auto take = [&](size_t bytes) -> char* {
    char* p = ws + off;
    off += (bytes + 255) & ~(size_t)255;
    return p;
  };
  int* flags            = (int*)take(256);
  unsigned short* xb    = (unsigned short*)take((size_t)DM * DH * 2);
  unsigned short* wtqkv = (unsigned short*)take((size_t)DNQKV * DH * 2);
  unsigned short* wto   = (unsigned short*)take((size_t)DH * DH * 2);
  unsigned short* qws   = (unsigned short*)take((size_t)DB * DNH * DS * DHD * 2);
  unsigned short* kws   = (unsigned short*)take((size_t)DB * DKVH * DS * DHD * 2);
  unsigned short* vtws  = (unsigned short*)take((size_t)DB * DKVH * DS * DHD * 2);
  unsigned short* ctx   = (unsigned short*)take((size_t)DM * DNH * DHD * 2);

  detect_mode<<<1, 64, 0, stream>>>((const unsigned short*)wq, flags);
  convert_x<<<DM * DH / 8 / 256, 256, 0, stream>>>(hs, xb, flags, DM * DH);
  transpose_w<<<dim3(64, 64), 256, 0, stream>>>(wq, wtqkv, flags, 2048, 2048);
  transpose_w<<<dim3(16, 64), 256, 0, stream>>>(wk, wtqkv + (size_t)2048 * 2048, flags, 2048, 512);
  transpose_w<<<dim3(16, 64), 256, 0, stream>>>(wv, wtqkv + (size_t)2560 * 2048, flags, 2048, 512);
  transpose_w<<<dim3(64, 64), 256, 0, stream>>>(wo, wto, flags, 2048, 2048);

  gemm_qkv<<<dim3(192), 512, 0, stream>>>(xb, wtqkv, pos, qws, kws, vtws);

  flash_attn<<<dim3(16, DB * DNH), 256, 0, stream>>>(qws, kws, vtws, ctx);

  gemm_out<<<dim3(256), 512, 0, stream>>>(ctx, wto, (unsigned short*)d_out, (float*)d_out, flags);
}